// Round 12
// baseline (361.870 us; speedup 1.0000x reference)
//
#include <hip/hip_runtime.h>

#define H 64

typedef __attribute__((ext_vector_type(8))) short short8;
typedef __attribute__((ext_vector_type(4))) float floatx4;

__device__ __forceinline__ short bf16r(float f) {
    union { float f; unsigned u; } v; v.f = f;
    unsigned r = v.u + 0x7FFFu + ((v.u >> 16) & 1u);
    return (short)(r >> 16);
}

__device__ __forceinline__ float b2f(unsigned short s) {
    union { unsigned u; float f; } v; v.u = ((unsigned)s) << 16; return v.f;
}

// ---------------- fused prep: weight B-frag packing + x->bf16 ----------------
__device__ __forceinline__ void pack_one(const float* W, short* out, int K, int KT, int tid)
{
    const int lane = tid & 63;
    const int nt = (tid >> 6) & 3;
    const int lk = tid >> 8;          // lay*KT + kt
    const int kt = lk % KT;
    const int lay = lk / KT;
    const int n = nt * 16 + (lane & 15);
    const int kbase = kt * 32 + ((lane >> 4) & 3) * 8;
    short8 v;
#pragma unroll
    for (int j = 0; j < 8; ++j) {
        const int k = kbase + j;
        const float w = (k < K) ? W[((size_t)lay * K + k) * H + n] : 0.f;
        v[j] = bf16r(w);
    }
    *(short8*)(out + (size_t)tid * 8) = v;
}

#define T_MW1 3840   // 3*5*4*64  (edge W1: K=144 padded to 160)
#define T_NW1 3072   // 3*4*4*64  (node fused W1: K=128)
#define T_UW2 1536   // 3*2*4*64

// W2u[l] = mW2[l] @ uW1b[l]   (folds message-GEMM2 into node update)
// nW1cat[l] = [uW1a ; W2u]  (128 x 64 fp32),  c2u[l][j] = sum_c mb2[c]*uW1[64+c][j]
__global__ void prep_w2u(const float* __restrict__ mW2, const float* __restrict__ uW1,
                         const float* __restrict__ mb2,
                         float* __restrict__ nW1cat, float* __restrict__ c2u)
{
    int g = blockIdx.x * blockDim.x + threadIdx.x;
    if (g < 12288) {                       // W2u: 3 * 64 * 64
        const int l = g >> 12, rem = g & 4095, a = rem >> 6, j = rem & 63;
        float s = 0.f;
#pragma unroll 8
        for (int c = 0; c < 64; ++c)
            s += mW2[((size_t)l * 64 + a) * 64 + c] * uW1[((size_t)l * 128 + 64 + c) * 64 + j];
        nW1cat[((size_t)l * 128 + 64 + a) * 64 + j] = s;
        return;
    }
    g -= 12288;
    if (g < 12288) {                       // copy uW1a rows 0..63
        const int l = g >> 12, rem = g & 4095;
        nW1cat[(size_t)l * 8192 + rem] = uW1[(size_t)l * 8192 + rem];
        return;
    }
    g -= 12288;
    if (g < 192) {                         // c2u
        const int l = g >> 6, j = g & 63;
        float s = 0.f;
#pragma unroll 8
        for (int c = 0; c < 64; ++c)
            s += mb2[l * 64 + c] * uW1[((size_t)l * 128 + 64 + c) * 64 + j];
        c2u[l * 64 + j] = s;
    }
}

__global__ void prep_all(const float* __restrict__ mW1, const float* __restrict__ nW1cat,
                         const float* __restrict__ uW2, const float* __restrict__ x,
                         short* __restrict__ mW1f, short* __restrict__ nW1f,
                         short* __restrict__ uW2f, short* __restrict__ x16, int n8)
{
    int g = blockIdx.x * blockDim.x + threadIdx.x;
    if (g < T_MW1) { pack_one(mW1, mW1f, 144, 5, g); return; }
    g -= T_MW1;
    if (g < T_NW1) { pack_one(nW1cat, nW1f, 128, 4, g); return; }
    g -= T_NW1;
    if (g < T_UW2) { pack_one(uW2, uW2f, 64, 2, g); return; }
    g -= T_UW2;
    if (g < n8) {
        const float4 a = ((const float4*)x)[2 * g];
        const float4 b = ((const float4*)x)[2 * g + 1];
        short8 v;
        v[0] = bf16r(a.x); v[1] = bf16r(a.y); v[2] = bf16r(a.z); v[3] = bf16r(a.w);
        v[4] = bf16r(b.x); v[5] = bf16r(b.y); v[6] = bf16r(b.z); v[7] = bf16r(b.w);
        ((short8*)x16)[g] = v;
    }
}

// ---------------- dst-sort prep: ONE atomic pass (rank) + no-atomic scatter ----
__global__ void rank_pass(const int* __restrict__ edst, int* __restrict__ cnt,
                          int* __restrict__ rank4, int E)
{
    int e = blockIdx.x * blockDim.x + threadIdx.x;
    if (e < E) rank4[e] = atomicAdd(&cnt[edst[e]], 1);   // cnt -> degrees
}

__global__ void scan_block(const int* __restrict__ cnt, int* __restrict__ offs,
                           int* __restrict__ bsum, int n)
{
    __shared__ int buf[1024];
    const int t = threadIdx.x;
    const int gid = blockIdx.x * 1024 + t;
    const int v = (gid < n) ? cnt[gid] : 0;
    buf[t] = v;
    __syncthreads();
#pragma unroll
    for (int off = 1; off < 1024; off <<= 1) {
        int x = (t >= off) ? buf[t - off] : 0;
        __syncthreads();
        buf[t] += x;
        __syncthreads();
    }
    if (gid < n) offs[gid] = buf[t] - v;          // exclusive within block
    if (t == 1023) bsum[blockIdx.x] = buf[1023];
}

__global__ void scan_bsum(int* __restrict__ bsum, int nb)
{
    if (threadIdx.x == 0) {
        int acc = 0;
        for (int i = 0; i < nb; ++i) { int v = bsum[i]; bsum[i] = acc; acc += v; }
    }
}

__global__ void add_bsum(int* __restrict__ offs, const int* __restrict__ bsum, int n)
{
    int gid = blockIdx.x * blockDim.x + threadIdx.x;
    if (gid < n) offs[gid] += bsum[gid >> 10];
}

// deterministic scatter: p = offs[d] + rank[e]; all reads sequential, zero
// atomics, ONE random region: 64B-aligned record {src,dst,pad8,ea32,pad16}
// written as 4x16B = full line (no RMW fetch, one line touch per edge).
__global__ void reorder_scatter(const int* __restrict__ esrc, const int* __restrict__ edst,
                                const int* __restrict__ rank4, const int* __restrict__ offs,
                                const float* __restrict__ ea,
                                char* __restrict__ rec, int E)
{
    int e = blockIdx.x * blockDim.x + threadIdx.x;
    if (e >= E) return;
    const int d = edst[e];
    const int p = offs[d] + rank4[e];
    const float4* r = (const float4*)(ea + (size_t)e * 16);
    const float4 a = r[0], b = r[1], c = r[2], d4 = r[3];
    short8 v0, v1;
    v0[0] = bf16r(a.x); v0[1] = bf16r(a.y); v0[2] = bf16r(a.z); v0[3] = bf16r(a.w);
    v0[4] = bf16r(b.x); v0[5] = bf16r(b.y); v0[6] = bf16r(b.z); v0[7] = bf16r(b.w);
    v1[0] = bf16r(c.x); v1[1] = bf16r(c.y); v1[2] = bf16r(c.z); v1[3] = bf16r(c.w);
    v1[4] = bf16r(d4.x); v1[5] = bf16r(d4.y); v1[6] = bf16r(d4.z); v1[7] = bf16r(d4.w);
    int4* rb = (int4*)(rec + (size_t)p * 64);
    rb[0] = make_int4(esrc[e], d, 0, 0);
    *(short8*)(rb + 1) = v0;
    *(short8*)(rb + 2) = v1;
    rb[3] = make_int4(0, 0, 0, 0);
}

// ---------------- per-layer node GEMM: P = h@mW1a, Q = h@mW1b (bf16 out) -------
__global__ __launch_bounds__(256, 5)
void pq_gemm(const short* __restrict__ h16, const short* __restrict__ W1fl,
             short* __restrict__ P16, short* __restrict__ Q16, int N)
{
    const int t = threadIdx.x;
    const int w = t >> 6, l = t & 63, q = l >> 4, m15 = l & 15;
    const int n0 = blockIdx.x * 64;
    const int n = n0 + w * 16 + m15;
    const bool ok = n < N;

    short8 a0 = {0,0,0,0,0,0,0,0}, a1 = a0;
    if (ok) {
        a0 = *(const short8*)(h16 + (size_t)n * H + q * 8);
        a1 = *(const short8*)(h16 + (size_t)n * H + 32 + q * 8);
    }

    floatx4 pa[4] = {{0,0,0,0},{0,0,0,0},{0,0,0,0},{0,0,0,0}};
    floatx4 qa[4] = {{0,0,0,0},{0,0,0,0},{0,0,0,0},{0,0,0,0}};
#pragma unroll
    for (int nt = 0; nt < 4; ++nt) {
        pa[nt] = __builtin_amdgcn_mfma_f32_16x16x32_bf16(a0, *(const short8*)(W1fl + ((0*4+nt)*64 + l)*8), pa[nt], 0,0,0);
        pa[nt] = __builtin_amdgcn_mfma_f32_16x16x32_bf16(a1, *(const short8*)(W1fl + ((1*4+nt)*64 + l)*8), pa[nt], 0,0,0);
        qa[nt] = __builtin_amdgcn_mfma_f32_16x16x32_bf16(a0, *(const short8*)(W1fl + ((2*4+nt)*64 + l)*8), qa[nt], 0,0,0);
        qa[nt] = __builtin_amdgcn_mfma_f32_16x16x32_bf16(a1, *(const short8*)(W1fl + ((3*4+nt)*64 + l)*8), qa[nt], 0,0,0);
    }
#pragma unroll
    for (int nt = 0; nt < 4; ++nt)
#pragma unroll
        for (int r = 0; r < 4; ++r) {
            const int nn = n0 + w * 16 + q * 4 + r;
            if (nn < N) {
                P16[(size_t)nn * H + nt * 16 + m15] = bf16r(pa[nt][r]);
                Q16[(size_t)nn * H + nt * 16 + m15] = bf16r(qa[nt][r]);
            }
        }
}

// ---------------- edge kernel: z = P[dst]+Q[src]+ea@W1c+b1; scatter relu(z) ----
// sd + ea come from ONE 64B record line (L1 reuse across the two accesses).
__global__ __launch_bounds__(256, 5)
void edge_msg_mfma(const short* __restrict__ P16, const short* __restrict__ Q16,
                   const char* __restrict__ rec,
                   const short* __restrict__ W1cf, const float* __restrict__ b1,
                   float* __restrict__ aggH)
{
    __shared__ float smf[4 * 1056];          // 4 waves x [16][66] fp32
    const int t = threadIdx.x;
    const int w = t >> 6, l = t & 63, q = l >> 4, m15 = l & 15;
    const int i = blockIdx.x * 64 + w * 16 + m15;
    const char* rbase = rec + (size_t)i * 64;
    const int2 sd = *(const int2*)rbase;
    const int s = sd.x, d = sd.y;
    float* C2 = smf + w * 1056;

    int dm[16], sm[16];
#pragma unroll
    for (int mm = 0; mm < 16; ++mm) {
        dm[mm] = __builtin_amdgcn_readlane(d, mm);
        sm[mm] = __builtin_amdgcn_readlane(s, mm);
    }
    float pv[16], qv[16];
#pragma unroll
    for (int mm = 0; mm < 16; ++mm) {
        pv[mm] = b2f((unsigned short)P16[(size_t)dm[mm] * H + l]);
        qv[mm] = b2f((unsigned short)Q16[(size_t)sm[mm] * H + l]);
    }
    const float b1l = b1[l];

    short8 a4 = {0, 0, 0, 0, 0, 0, 0, 0};
    if (q < 2) a4 = *(const short8*)(rbase + 16 + q * 16);

    floatx4 r4[4];
#pragma unroll
    for (int nt = 0; nt < 4; ++nt) {
        floatx4 z0 = {0, 0, 0, 0};
        r4[nt] = __builtin_amdgcn_mfma_f32_16x16x32_bf16(a4, *(const short8*)(W1cf + (nt*64 + l)*8), z0, 0,0,0);
    }
#pragma unroll
    for (int nt = 0; nt < 4; ++nt)
#pragma unroll
        for (int r = 0; r < 4; ++r)
            C2[(q * 4 + r) * 66 + nt * 16 + m15] = r4[nt][r];

    float run; int cur;
    {
        run = fmaxf(C2[l] + pv[0] + qv[0] + b1l, 0.f);
        cur = dm[0];
    }
#pragma unroll
    for (int mm = 1; mm < 16; ++mm) {
        const float val = fmaxf(C2[mm * 66 + l] + pv[mm] + qv[mm] + b1l, 0.f);
        if (dm[mm] != cur) {
            atomicAdd(&aggH[(size_t)cur * H + l], run);
            run = val; cur = dm[mm];
        } else {
            run += val;
        }
    }
    atomicAdd(&aggH[(size_t)cur * H + l], run);
}

// ---------------- node-update MLP: zero-LDS A-path ----------------
__global__ __launch_bounds__(256, 5)
void node_update_mfma(const short* __restrict__ h16,
                      const float* __restrict__ aggH,
                      const short* __restrict__ W1f, const float* __restrict__ b1,
                      const short* __restrict__ W2f, const float* __restrict__ b2,
                      const float* __restrict__ c2u, const int* __restrict__ degc,
                      short* __restrict__ h16out,        // non-final
                      const int* __restrict__ batch,     // final
                      float* __restrict__ pooled, float* __restrict__ counts,
                      int N)
{
    __shared__ char smraw[16896];
    const int t = threadIdx.x;
    const int w = t >> 6, l = t & 63, q = l >> 4, m15 = l & 15;
    const int n0 = blockIdx.x * 64;
    const int n = n0 + w * 16 + m15;
    const bool ok = n < N;

    short* C1 = (short*)(smraw + w * 4224);
    float* C2 = (float*)(smraw + w * 4224);

    short8 a0 = {0,0,0,0,0,0,0,0}, a1 = a0, a2 = a0, a3 = a0;
    if (ok) {
        a0 = *(const short8*)(h16 + (size_t)n * H + q * 8);
        a1 = *(const short8*)(h16 + (size_t)n * H + 32 + q * 8);
        const float4 f0 = *(const float4*)(aggH + (size_t)n * H + q * 8);
        const float4 f1 = *(const float4*)(aggH + (size_t)n * H + q * 8 + 4);
        const float4 f2 = *(const float4*)(aggH + (size_t)n * H + 32 + q * 8);
        const float4 f3 = *(const float4*)(aggH + (size_t)n * H + 32 + q * 8 + 4);
        a2[0] = bf16r(f0.x); a2[1] = bf16r(f0.y); a2[2] = bf16r(f0.z); a2[3] = bf16r(f0.w);
        a2[4] = bf16r(f1.x); a2[5] = bf16r(f1.y); a2[6] = bf16r(f1.z); a2[7] = bf16r(f1.w);
        a3[0] = bf16r(f2.x); a3[1] = bf16r(f2.y); a3[2] = bf16r(f2.z); a3[3] = bf16r(f2.w);
        a3[4] = bf16r(f3.x); a3[5] = bf16r(f3.y); a3[6] = bf16r(f3.z); a3[7] = bf16r(f3.w);
    }

    float b1v[4], b2v[4], c2uv[4];
#pragma unroll
    for (int nt = 0; nt < 4; ++nt) {
        b1v[nt] = b1[nt * 16 + m15];
        b2v[nt] = b2[nt * 16 + m15];
        c2uv[nt] = c2u[nt * 16 + m15];
    }
    float degf[4];
#pragma unroll
    for (int r = 0; r < 4; ++r) {
        const int nn = n0 + w * 16 + q * 4 + r;
        degf[r] = (nn < N) ? (float)degc[nn] : 0.f;
    }

    floatx4 acc[4] = {{0,0,0,0},{0,0,0,0},{0,0,0,0},{0,0,0,0}};
#pragma unroll
    for (int nt = 0; nt < 4; ++nt) {
        acc[nt] = __builtin_amdgcn_mfma_f32_16x16x32_bf16(a0, *(const short8*)(W1f + ((0*4+nt)*64 + l)*8), acc[nt], 0,0,0);
        acc[nt] = __builtin_amdgcn_mfma_f32_16x16x32_bf16(a1, *(const short8*)(W1f + ((1*4+nt)*64 + l)*8), acc[nt], 0,0,0);
        acc[nt] = __builtin_amdgcn_mfma_f32_16x16x32_bf16(a2, *(const short8*)(W1f + ((2*4+nt)*64 + l)*8), acc[nt], 0,0,0);
        acc[nt] = __builtin_amdgcn_mfma_f32_16x16x32_bf16(a3, *(const short8*)(W1f + ((3*4+nt)*64 + l)*8), acc[nt], 0,0,0);
    }

#pragma unroll
    for (int nt = 0; nt < 4; ++nt)
#pragma unroll
        for (int r = 0; r < 4; ++r)
            C1[(q * 4 + r) * 72 + nt * 16 + m15] =
                bf16r(fmaxf(acc[nt][r] + b1v[nt] + degf[r] * c2uv[nt], 0.f));

    const short8 p0 = *(const short8*)(C1 + m15 * 72 + q * 8);
    const short8 p1 = *(const short8*)(C1 + m15 * 72 + 32 + q * 8);

    floatx4 c2[4] = {{0,0,0,0},{0,0,0,0},{0,0,0,0},{0,0,0,0}};
#pragma unroll
    for (int nt = 0; nt < 4; ++nt) {
        c2[nt] = __builtin_amdgcn_mfma_f32_16x16x32_bf16(p0, *(const short8*)(W2f + ((0*4+nt)*64 + l)*8), c2[nt], 0,0,0);
        c2[nt] = __builtin_amdgcn_mfma_f32_16x16x32_bf16(p1, *(const short8*)(W2f + ((1*4+nt)*64 + l)*8), c2[nt], 0,0,0);
    }

    if (!batch) {
#pragma unroll
        for (int nt = 0; nt < 4; ++nt)
#pragma unroll
            for (int r = 0; r < 4; ++r) {
                const int nn = n0 + w * 16 + q * 4 + r;
                if (nn < N)
                    h16out[(size_t)nn * H + nt * 16 + m15] =
                        bf16r(fmaxf(c2[nt][r] + b2v[nt], 0.f));
            }
        return;
    }

    // final layer: outer relu -> C2 -> register run-merge mean-pool
#pragma unroll
    for (int nt = 0; nt < 4; ++nt)
#pragma unroll
        for (int r = 0; r < 4; ++r)
            C2[(q * 4 + r) * 66 + nt * 16 + m15] = fmaxf(c2[nt][r] + b2v[nt], 0.f);

    const int bi = ok ? batch[n] : -1;
    int bm[16];
#pragma unroll
    for (int mm = 0; mm < 16; ++mm)
        bm[mm] = __builtin_amdgcn_readlane(bi, mm);
    float v[16];
#pragma unroll
    for (int mm = 0; mm < 16; ++mm) v[mm] = C2[mm * 66 + l];

    float run = v[0];
    int cur = bm[0];
    int len = 1;
#pragma unroll
    for (int mm = 1; mm < 16; ++mm) {
        if (bm[mm] != cur) {
            if (cur >= 0) {
                atomicAdd(&pooled[(size_t)cur * H + l], run);
                if (l == 0) atomicAdd(&counts[cur], (float)len);
            }
            run = v[mm]; cur = bm[mm]; len = 1;
        } else {
            run += v[mm]; ++len;
        }
    }
    if (cur >= 0) {
        atomicAdd(&pooled[(size_t)cur * H + l], run);
        if (l == 0) atomicAdd(&counts[cur], (float)len);
    }
}

// ---------------- head ----------------
__global__ void head_kernel(const float* __restrict__ pooled,
                            const float* __restrict__ counts,
                            const float* __restrict__ lin1w,
                            const float* __restrict__ lin1b,
                            const float* __restrict__ lin2w,
                            const float* __restrict__ lin2b,
                            float* __restrict__ out, int G)
{
    int g = blockIdx.x;
    int j = threadIdx.x;
    __shared__ float p[H];
    float c = fmaxf(counts[g], 1.0f);
    p[j] = pooled[(size_t)g * H + j] / c;
    __syncthreads();

    float accj = lin1b[j];
#pragma unroll
    for (int k = 0; k < H; ++k) accj = fmaf(p[k], lin1w[k * H + j], accj);
    accj = fmaxf(accj, 0.0f) * lin2w[j];
#pragma unroll
    for (int off = 32; off >= 1; off >>= 1) accj += __shfl_down(accj, off);
    if (j == 0) out[g] = accj + lin2b[0];
}

extern "C" void kernel_launch(void* const* d_in, const int* in_sizes, int n_in,
                              void* d_out, int out_size, void* d_ws, size_t ws_size,
                              hipStream_t stream)
{
    const float* x      = (const float*)d_in[0];
    const int*   eidx   = (const int*)d_in[1];
    const float* ea     = (const float*)d_in[2];
    const int*   batch  = (const int*)d_in[3];
    const float* mW1    = (const float*)d_in[4];
    const float* mb1    = (const float*)d_in[5];
    const float* mW2    = (const float*)d_in[6];
    const float* mb2    = (const float*)d_in[7];
    const float* uW1    = (const float*)d_in[8];
    const float* ub1    = (const float*)d_in[9];
    const float* uW2    = (const float*)d_in[10];
    const float* ub2    = (const float*)d_in[11];
    const float* lin1w  = (const float*)d_in[12];
    const float* lin1b  = (const float*)d_in[13];
    const float* lin2w  = (const float*)d_in[14];
    const float* lin2b  = (const float*)d_in[15];

    const int N = in_sizes[0] / H;
    const int E = in_sizes[1] / 2;
    const int G = out_size;

    // ---- workspace ----
    short* mW1f = (short*)d_ws;                  // 30720 shorts
    short* nW1f = mW1f + 30720;                  // 24576
    short* uW2f = nW1f + 24576;                  // 12288
    short* x16  = uW2f + 12288;                  // N*H
    short* h16A = x16  + (size_t)N * H;
    short* h16B = h16A + (size_t)N * H;
    short* P16  = h16B + (size_t)N * H;          // N*H bf16
    short* Q16  = P16  + (size_t)N * H;          // N*H bf16
    float* nW1cat = (float*)(Q16 + (size_t)N * H);     // 3*128*64
    float* c2u    = nW1cat + 3 * 128 * 64;             // 192
    char*  pch  = (char*)(c2u + 192);
    pch = (char*)(((uintptr_t)pch + 63) & ~(uintptr_t)63);
    char* rec   = pch;                pch += (size_t)E * 64;   // 64B records
    int* offs   = (int*)pch;          pch += (size_t)N * 4;
    int* bsum   = (int*)pch;          pch += 256;
    int* rank4  = (int*)pch;          pch += (size_t)E * 4;
    // contiguous zero region: [cnt N ints][agg3 3*N*H][pooled G*H][counts G]
    int*   cnt    = (int*)pch;
    float* agg3   = (float*)(pch + (size_t)N * 4);
    float* pooled = agg3 + (size_t)3 * N * H;
    float* counts = pooled + (size_t)G * H;
    const size_t zero_bytes = (size_t)N * 4 + ((size_t)3 * N * H + (size_t)G * H + G) * 4;

    const int* esrc = eidx;
    const int* edst = eidx + E;

    // ---- prep: fused node weights, then frag packing + x16 ----
    prep_w2u<<<(24768 + 255) / 256, 256, 0, stream>>>(mW2, uW1, mb2, nW1cat, c2u);
    {
        const int n8 = N * H / 8;
        const int total = T_MW1 + T_NW1 + T_UW2 + n8;
        prep_all<<<(total + 255) / 256, 256, 0, stream>>>(
            mW1, nW1cat, uW2, x, mW1f, nW1f, uW2f, x16, n8);
    }

    hipMemsetAsync(cnt, 0, zero_bytes, stream);

    // ---- dst-sort prep: single atomic pass + deterministic full-line scatter ----
    rank_pass<<<(E + 255) / 256, 256, 0, stream>>>(edst, cnt, rank4, E);
    {
        const int nb = (N + 1023) / 1024;
        scan_block<<<nb, 1024, 0, stream>>>(cnt, offs, bsum, N);
        scan_bsum<<<1, 64, 0, stream>>>(bsum, nb);
        add_bsum<<<(N + 255) / 256, 256, 0, stream>>>(offs, bsum, N);
    }
    reorder_scatter<<<(E + 255) / 256, 256, 0, stream>>>(
        esrc, edst, rank4, offs, ea, rec, E);

    const short* hin = x16;
    short* houts16[3] = {h16A, h16B, nullptr};
    const int nEB = E / 64;                      // 12500 exact
    const int nNB = (N + 63) / 64;

    for (int lyr = 0; lyr < 3; ++lyr) {
        float* agg = agg3 + (size_t)lyr * N * H;
        pq_gemm<<<nNB, 256, 0, stream>>>(
            hin, mW1f + (size_t)lyr * 10240, P16, Q16, N);
        edge_msg_mfma<<<nEB, 256, 0, stream>>>(
            P16, Q16, rec,
            mW1f + (size_t)lyr * 10240 + 8192,   // kt=4 block = ea weights
            mb1 + (size_t)lyr * H,
            agg);
        node_update_mfma<<<nNB, 256, 0, stream>>>(
            hin, agg,
            nW1f + (size_t)lyr * 8192, ub1 + (size_t)lyr * H,
            uW2f + (size_t)lyr * 4096, ub2 + (size_t)lyr * H,
            c2u + (size_t)lyr * 64, cnt,
            houts16[lyr],
            (lyr == 2) ? batch : (const int*)nullptr,
            pooled, counts, N);
        hin = houts16[lyr];
    }

    head_kernel<<<G, H, 0, stream>>>(pooled, counts, lin1w, lin1b, lin2w, lin2b,
                                     (float*)d_out, G);
}

// Round 13
// 358.617 us; speedup vs baseline: 1.0091x; 1.0091x over previous
//
#include <hip/hip_runtime.h>

#define H 64

typedef __attribute__((ext_vector_type(8))) short short8;
typedef __attribute__((ext_vector_type(4))) float floatx4;

__device__ __forceinline__ short bf16r(float f) {
    union { float f; unsigned u; } v; v.f = f;
    unsigned r = v.u + 0x7FFFu + ((v.u >> 16) & 1u);
    return (short)(r >> 16);
}

__device__ __forceinline__ float b2f(unsigned short s) {
    union { unsigned u; float f; } v; v.u = ((unsigned)s) << 16; return v.f;
}

// ---------------- fused prep: weight B-frag packing + x->bf16 ----------------
__device__ __forceinline__ void pack_one(const float* W, short* out, int K, int KT, int tid)
{
    const int lane = tid & 63;
    const int nt = (tid >> 6) & 3;
    const int lk = tid >> 8;          // lay*KT + kt
    const int kt = lk % KT;
    const int lay = lk / KT;
    const int n = nt * 16 + (lane & 15);
    const int kbase = kt * 32 + ((lane >> 4) & 3) * 8;
    short8 v;
#pragma unroll
    for (int j = 0; j < 8; ++j) {
        const int k = kbase + j;
        const float w = (k < K) ? W[((size_t)lay * K + k) * H + n] : 0.f;
        v[j] = bf16r(w);
    }
    *(short8*)(out + (size_t)tid * 8) = v;
}

#define T_MW1 3840   // 3*5*4*64  (edge W1: K=144 padded to 160)
#define T_NW1 3072   // 3*4*4*64  (node fused W1: K=128)
#define T_UW2 1536   // 3*2*4*64

// W2u[l] = mW2[l] @ uW1b[l]   (folds message-GEMM2 into node update)
// nW1cat[l] = [uW1a ; W2u]  (128 x 64 fp32),  c2u[l][j] = sum_c mb2[c]*uW1[64+c][j]
__global__ void prep_w2u(const float* __restrict__ mW2, const float* __restrict__ uW1,
                         const float* __restrict__ mb2,
                         float* __restrict__ nW1cat, float* __restrict__ c2u)
{
    int g = blockIdx.x * blockDim.x + threadIdx.x;
    if (g < 12288) {                       // W2u: 3 * 64 * 64
        const int l = g >> 12, rem = g & 4095, a = rem >> 6, j = rem & 63;
        float s = 0.f;
#pragma unroll 8
        for (int c = 0; c < 64; ++c)
            s += mW2[((size_t)l * 64 + a) * 64 + c] * uW1[((size_t)l * 128 + 64 + c) * 64 + j];
        nW1cat[((size_t)l * 128 + 64 + a) * 64 + j] = s;
        return;
    }
    g -= 12288;
    if (g < 12288) {                       // copy uW1a rows 0..63
        const int l = g >> 12, rem = g & 4095;
        nW1cat[(size_t)l * 8192 + rem] = uW1[(size_t)l * 8192 + rem];
        return;
    }
    g -= 12288;
    if (g < 192) {                         // c2u
        const int l = g >> 6, j = g & 63;
        float s = 0.f;
#pragma unroll 8
        for (int c = 0; c < 64; ++c)
            s += mb2[l * 64 + c] * uW1[((size_t)l * 128 + 64 + c) * 64 + j];
        c2u[l * 64 + j] = s;
    }
}

__global__ void prep_all(const float* __restrict__ mW1, const float* __restrict__ nW1cat,
                         const float* __restrict__ uW2, const float* __restrict__ x,
                         short* __restrict__ mW1f, short* __restrict__ nW1f,
                         short* __restrict__ uW2f, short* __restrict__ x16, int n8)
{
    int g = blockIdx.x * blockDim.x + threadIdx.x;
    if (g < T_MW1) { pack_one(mW1, mW1f, 144, 5, g); return; }
    g -= T_MW1;
    if (g < T_NW1) { pack_one(nW1cat, nW1f, 128, 4, g); return; }
    g -= T_NW1;
    if (g < T_UW2) { pack_one(uW2, uW2f, 64, 2, g); return; }
    g -= T_UW2;
    if (g < n8) {
        const float4 a = ((const float4*)x)[2 * g];
        const float4 b = ((const float4*)x)[2 * g + 1];
        short8 v;
        v[0] = bf16r(a.x); v[1] = bf16r(a.y); v[2] = bf16r(a.z); v[3] = bf16r(a.w);
        v[4] = bf16r(b.x); v[5] = bf16r(b.y); v[6] = bf16r(b.z); v[7] = bf16r(b.w);
        ((short8*)x16)[g] = v;
    }
}

// ---------------- dst-sort prep: ONE atomic pass (rank) + no-atomic scatter ----
__global__ void rank_pass(const int* __restrict__ edst, int* __restrict__ cnt,
                          int* __restrict__ rank4, int E)
{
    int e = blockIdx.x * blockDim.x + threadIdx.x;
    if (e < E) rank4[e] = atomicAdd(&cnt[edst[e]], 1);   // cnt -> degrees
}

__global__ void scan_block(const int* __restrict__ cnt, int* __restrict__ offs,
                           int* __restrict__ bsum, int n)
{
    __shared__ int buf[1024];
    const int t = threadIdx.x;
    const int gid = blockIdx.x * 1024 + t;
    const int v = (gid < n) ? cnt[gid] : 0;
    buf[t] = v;
    __syncthreads();
#pragma unroll
    for (int off = 1; off < 1024; off <<= 1) {
        int x = (t >= off) ? buf[t - off] : 0;
        __syncthreads();
        buf[t] += x;
        __syncthreads();
    }
    if (gid < n) offs[gid] = buf[t] - v;          // exclusive within block
    if (t == 1023) bsum[blockIdx.x] = buf[1023];
}

__global__ void scan_bsum(int* __restrict__ bsum, int nb)
{
    if (threadIdx.x == 0) {
        int acc = 0;
        for (int i = 0; i < nb; ++i) { int v = bsum[i]; bsum[i] = acc; acc += v; }
    }
}

__global__ void add_bsum(int* __restrict__ offs, const int* __restrict__ bsum, int n)
{
    int gid = blockIdx.x * blockDim.x + threadIdx.x;
    if (gid < n) offs[gid] += bsum[gid >> 10];
}

// deterministic scatter: p = offs[d] + rank[e]; all reads sequential, zero
// atomics, ONE random region: 64B-aligned record {src,dst,pad8,ea32,pad16}
__global__ void reorder_scatter(const int* __restrict__ esrc, const int* __restrict__ edst,
                                const int* __restrict__ rank4, const int* __restrict__ offs,
                                const float* __restrict__ ea,
                                char* __restrict__ rec, int E)
{
    int e = blockIdx.x * blockDim.x + threadIdx.x;
    if (e >= E) return;
    const int d = edst[e];
    const int p = offs[d] + rank4[e];
    const float4* r = (const float4*)(ea + (size_t)e * 16);
    const float4 a = r[0], b = r[1], c = r[2], d4 = r[3];
    short8 v0, v1;
    v0[0] = bf16r(a.x); v0[1] = bf16r(a.y); v0[2] = bf16r(a.z); v0[3] = bf16r(a.w);
    v0[4] = bf16r(b.x); v0[5] = bf16r(b.y); v0[6] = bf16r(b.z); v0[7] = bf16r(b.w);
    v1[0] = bf16r(c.x); v1[1] = bf16r(c.y); v1[2] = bf16r(c.z); v1[3] = bf16r(c.w);
    v1[4] = bf16r(d4.x); v1[5] = bf16r(d4.y); v1[6] = bf16r(d4.z); v1[7] = bf16r(d4.w);
    int4* rb = (int4*)(rec + (size_t)p * 64);
    rb[0] = make_int4(esrc[e], d, 0, 0);
    *(short8*)(rb + 1) = v0;
    *(short8*)(rb + 2) = v1;
    rb[3] = make_int4(0, 0, 0, 0);
}

// ---------------- layer-0 node GEMM: P = x@mW1a, Q = x@mW1b (bf16 out) --------
// (layers 1,2 P/Q are produced fused inside node_update_fused)
__global__ __launch_bounds__(256, 5)
void pq_gemm(const short* __restrict__ h16, const short* __restrict__ W1fl,
             short* __restrict__ P16, short* __restrict__ Q16, int N)
{
    const int t = threadIdx.x;
    const int w = t >> 6, l = t & 63, q = l >> 4, m15 = l & 15;
    const int n0 = blockIdx.x * 64;
    const int n = n0 + w * 16 + m15;
    const bool ok = n < N;

    short8 a0 = {0,0,0,0,0,0,0,0}, a1 = a0;
    if (ok) {
        a0 = *(const short8*)(h16 + (size_t)n * H + q * 8);
        a1 = *(const short8*)(h16 + (size_t)n * H + 32 + q * 8);
    }

    floatx4 pa[4] = {{0,0,0,0},{0,0,0,0},{0,0,0,0},{0,0,0,0}};
    floatx4 qa[4] = {{0,0,0,0},{0,0,0,0},{0,0,0,0},{0,0,0,0}};
#pragma unroll
    for (int nt = 0; nt < 4; ++nt) {
        pa[nt] = __builtin_amdgcn_mfma_f32_16x16x32_bf16(a0, *(const short8*)(W1fl + ((0*4+nt)*64 + l)*8), pa[nt], 0,0,0);
        pa[nt] = __builtin_amdgcn_mfma_f32_16x16x32_bf16(a1, *(const short8*)(W1fl + ((1*4+nt)*64 + l)*8), pa[nt], 0,0,0);
        qa[nt] = __builtin_amdgcn_mfma_f32_16x16x32_bf16(a0, *(const short8*)(W1fl + ((2*4+nt)*64 + l)*8), qa[nt], 0,0,0);
        qa[nt] = __builtin_amdgcn_mfma_f32_16x16x32_bf16(a1, *(const short8*)(W1fl + ((3*4+nt)*64 + l)*8), qa[nt], 0,0,0);
    }
#pragma unroll
    for (int nt = 0; nt < 4; ++nt)
#pragma unroll
        for (int r = 0; r < 4; ++r) {
            const int nn = n0 + w * 16 + q * 4 + r;
            if (nn < N) {
                P16[(size_t)nn * H + nt * 16 + m15] = bf16r(pa[nt][r]);
                Q16[(size_t)nn * H + nt * 16 + m15] = bf16r(qa[nt][r]);
            }
        }
}

// ---------------- edge kernel: z = P[dst]+Q[src]+ea@W1c+b1; scatter relu(z) ----
__global__ __launch_bounds__(256, 5)
void edge_msg_mfma(const short* __restrict__ P16, const short* __restrict__ Q16,
                   const char* __restrict__ rec,
                   const short* __restrict__ W1cf, const float* __restrict__ b1,
                   float* __restrict__ aggH)
{
    __shared__ float smf[4 * 1056];          // 4 waves x [16][66] fp32
    const int t = threadIdx.x;
    const int w = t >> 6, l = t & 63, q = l >> 4, m15 = l & 15;
    const int i = blockIdx.x * 64 + w * 16 + m15;
    const char* rbase = rec + (size_t)i * 64;
    const int2 sd = *(const int2*)rbase;
    const int s = sd.x, d = sd.y;
    float* C2 = smf + w * 1056;

    int dm[16], sm[16];
#pragma unroll
    for (int mm = 0; mm < 16; ++mm) {
        dm[mm] = __builtin_amdgcn_readlane(d, mm);
        sm[mm] = __builtin_amdgcn_readlane(s, mm);
    }
    float pv[16], qv[16];
#pragma unroll
    for (int mm = 0; mm < 16; ++mm) {
        pv[mm] = b2f((unsigned short)P16[(size_t)dm[mm] * H + l]);
        qv[mm] = b2f((unsigned short)Q16[(size_t)sm[mm] * H + l]);
    }
    const float b1l = b1[l];

    short8 a4 = {0, 0, 0, 0, 0, 0, 0, 0};
    if (q < 2) a4 = *(const short8*)(rbase + 16 + q * 16);

    floatx4 r4[4];
#pragma unroll
    for (int nt = 0; nt < 4; ++nt) {
        floatx4 z0 = {0, 0, 0, 0};
        r4[nt] = __builtin_amdgcn_mfma_f32_16x16x32_bf16(a4, *(const short8*)(W1cf + (nt*64 + l)*8), z0, 0,0,0);
    }
#pragma unroll
    for (int nt = 0; nt < 4; ++nt)
#pragma unroll
        for (int r = 0; r < 4; ++r)
            C2[(q * 4 + r) * 66 + nt * 16 + m15] = r4[nt][r];

    float run; int cur;
    {
        run = fmaxf(C2[l] + pv[0] + qv[0] + b1l, 0.f);
        cur = dm[0];
    }
#pragma unroll
    for (int mm = 1; mm < 16; ++mm) {
        const float val = fmaxf(C2[mm * 66 + l] + pv[mm] + qv[mm] + b1l, 0.f);
        if (dm[mm] != cur) {
            atomicAdd(&aggH[(size_t)cur * H + l], run);
            run = val; cur = dm[mm];
        } else {
            run += val;
        }
    }
    atomicAdd(&aggH[(size_t)cur * H + l], run);
}

// ---------------- node-update MLP (layers 0,1): + fused next-layer P/Q --------
// h_out -> global AND wave-private C1 -> A-frags -> 16 MFMAs produce next
// layer's P/Q (kills pq_gemm dispatch + h16 re-read). bounds (256,4) for the
// extra 32 accumulator VGPRs; final layer keeps its own (256,5) kernel.
__global__ __launch_bounds__(256, 4)
void node_update_fused(const short* __restrict__ h16,
                       const float* __restrict__ aggH,
                       const short* __restrict__ W1f, const float* __restrict__ b1,
                       const short* __restrict__ W2f, const float* __restrict__ b2,
                       const float* __restrict__ c2u, const int* __restrict__ degc,
                       short* __restrict__ h16out,
                       const short* __restrict__ W1fn,   // next-layer mW1 frags
                       short* __restrict__ P16o, short* __restrict__ Q16o,
                       int N)
{
    __shared__ char smraw[16896];
    const int t = threadIdx.x;
    const int w = t >> 6, l = t & 63, q = l >> 4, m15 = l & 15;
    const int n0 = blockIdx.x * 64;
    const int n = n0 + w * 16 + m15;
    const bool ok = n < N;

    short* C1 = (short*)(smraw + w * 4224);

    short8 a0 = {0,0,0,0,0,0,0,0}, a1 = a0, a2 = a0, a3 = a0;
    if (ok) {
        a0 = *(const short8*)(h16 + (size_t)n * H + q * 8);
        a1 = *(const short8*)(h16 + (size_t)n * H + 32 + q * 8);
        const float4 f0 = *(const float4*)(aggH + (size_t)n * H + q * 8);
        const float4 f1 = *(const float4*)(aggH + (size_t)n * H + q * 8 + 4);
        const float4 f2 = *(const float4*)(aggH + (size_t)n * H + 32 + q * 8);
        const float4 f3 = *(const float4*)(aggH + (size_t)n * H + 32 + q * 8 + 4);
        a2[0] = bf16r(f0.x); a2[1] = bf16r(f0.y); a2[2] = bf16r(f0.z); a2[3] = bf16r(f0.w);
        a2[4] = bf16r(f1.x); a2[5] = bf16r(f1.y); a2[6] = bf16r(f1.z); a2[7] = bf16r(f1.w);
        a3[0] = bf16r(f2.x); a3[1] = bf16r(f2.y); a3[2] = bf16r(f2.z); a3[3] = bf16r(f2.w);
        a3[4] = bf16r(f3.x); a3[5] = bf16r(f3.y); a3[6] = bf16r(f3.z); a3[7] = bf16r(f3.w);
    }

    float b1v[4], b2v[4], c2uv[4];
#pragma unroll
    for (int nt = 0; nt < 4; ++nt) {
        b1v[nt] = b1[nt * 16 + m15];
        b2v[nt] = b2[nt * 16 + m15];
        c2uv[nt] = c2u[nt * 16 + m15];
    }
    float degf[4];
#pragma unroll
    for (int r = 0; r < 4; ++r) {
        const int nn = n0 + w * 16 + q * 4 + r;
        degf[r] = (nn < N) ? (float)degc[nn] : 0.f;
    }

    floatx4 acc[4] = {{0,0,0,0},{0,0,0,0},{0,0,0,0},{0,0,0,0}};
#pragma unroll
    for (int nt = 0; nt < 4; ++nt) {
        acc[nt] = __builtin_amdgcn_mfma_f32_16x16x32_bf16(a0, *(const short8*)(W1f + ((0*4+nt)*64 + l)*8), acc[nt], 0,0,0);
        acc[nt] = __builtin_amdgcn_mfma_f32_16x16x32_bf16(a1, *(const short8*)(W1f + ((1*4+nt)*64 + l)*8), acc[nt], 0,0,0);
        acc[nt] = __builtin_amdgcn_mfma_f32_16x16x32_bf16(a2, *(const short8*)(W1f + ((2*4+nt)*64 + l)*8), acc[nt], 0,0,0);
        acc[nt] = __builtin_amdgcn_mfma_f32_16x16x32_bf16(a3, *(const short8*)(W1f + ((3*4+nt)*64 + l)*8), acc[nt], 0,0,0);
    }

#pragma unroll
    for (int nt = 0; nt < 4; ++nt)
#pragma unroll
        for (int r = 0; r < 4; ++r)
            C1[(q * 4 + r) * 72 + nt * 16 + m15] =
                bf16r(fmaxf(acc[nt][r] + b1v[nt] + degf[r] * c2uv[nt], 0.f));

    const short8 p0 = *(const short8*)(C1 + m15 * 72 + q * 8);
    const short8 p1 = *(const short8*)(C1 + m15 * 72 + 32 + q * 8);

    floatx4 c2[4] = {{0,0,0,0},{0,0,0,0},{0,0,0,0},{0,0,0,0}};
#pragma unroll
    for (int nt = 0; nt < 4; ++nt) {
        c2[nt] = __builtin_amdgcn_mfma_f32_16x16x32_bf16(p0, *(const short8*)(W2f + ((0*4+nt)*64 + l)*8), c2[nt], 0,0,0);
        c2[nt] = __builtin_amdgcn_mfma_f32_16x16x32_bf16(p1, *(const short8*)(W2f + ((1*4+nt)*64 + l)*8), c2[nt], 0,0,0);
    }

    // h_out bf16: to global AND to wave-private C1 (A-frag staging for P/Q)
#pragma unroll
    for (int nt = 0; nt < 4; ++nt)
#pragma unroll
        for (int r = 0; r < 4; ++r) {
            const short hv = bf16r(fmaxf(c2[nt][r] + b2v[nt], 0.f));
            C1[(q * 4 + r) * 72 + nt * 16 + m15] = hv;
            const int nn = n0 + w * 16 + q * 4 + r;
            if (nn < N)
                h16out[(size_t)nn * H + nt * 16 + m15] = hv;
        }

    const short8 h0 = *(const short8*)(C1 + m15 * 72 + q * 8);
    const short8 h1 = *(const short8*)(C1 + m15 * 72 + 32 + q * 8);
    floatx4 pa[4] = {{0,0,0,0},{0,0,0,0},{0,0,0,0},{0,0,0,0}};
    floatx4 qa[4] = {{0,0,0,0},{0,0,0,0},{0,0,0,0},{0,0,0,0}};
#pragma unroll
    for (int nt = 0; nt < 4; ++nt) {
        pa[nt] = __builtin_amdgcn_mfma_f32_16x16x32_bf16(h0, *(const short8*)(W1fn + ((0*4+nt)*64 + l)*8), pa[nt], 0,0,0);
        pa[nt] = __builtin_amdgcn_mfma_f32_16x16x32_bf16(h1, *(const short8*)(W1fn + ((1*4+nt)*64 + l)*8), pa[nt], 0,0,0);
        qa[nt] = __builtin_amdgcn_mfma_f32_16x16x32_bf16(h0, *(const short8*)(W1fn + ((2*4+nt)*64 + l)*8), qa[nt], 0,0,0);
        qa[nt] = __builtin_amdgcn_mfma_f32_16x16x32_bf16(h1, *(const short8*)(W1fn + ((3*4+nt)*64 + l)*8), qa[nt], 0,0,0);
    }
#pragma unroll
    for (int nt = 0; nt < 4; ++nt)
#pragma unroll
        for (int r = 0; r < 4; ++r) {
            const int nn = n0 + w * 16 + q * 4 + r;
            if (nn < N) {
                P16o[(size_t)nn * H + nt * 16 + m15] = bf16r(pa[nt][r]);
                Q16o[(size_t)nn * H + nt * 16 + m15] = bf16r(qa[nt][r]);
            }
        }
}

// ---------------- node-update MLP (final layer): fused mean-pool --------------
__global__ __launch_bounds__(256, 5)
void node_update_final(const short* __restrict__ h16,
                       const float* __restrict__ aggH,
                       const short* __restrict__ W1f, const float* __restrict__ b1,
                       const short* __restrict__ W2f, const float* __restrict__ b2,
                       const float* __restrict__ c2u, const int* __restrict__ degc,
                       const int* __restrict__ batch,
                       float* __restrict__ pooled, float* __restrict__ counts,
                       int N)
{
    __shared__ char smraw[16896];
    const int t = threadIdx.x;
    const int w = t >> 6, l = t & 63, q = l >> 4, m15 = l & 15;
    const int n0 = blockIdx.x * 64;
    const int n = n0 + w * 16 + m15;
    const bool ok = n < N;

    short* C1 = (short*)(smraw + w * 4224);
    float* C2 = (float*)(smraw + w * 4224);

    short8 a0 = {0,0,0,0,0,0,0,0}, a1 = a0, a2 = a0, a3 = a0;
    if (ok) {
        a0 = *(const short8*)(h16 + (size_t)n * H + q * 8);
        a1 = *(const short8*)(h16 + (size_t)n * H + 32 + q * 8);
        const float4 f0 = *(const float4*)(aggH + (size_t)n * H + q * 8);
        const float4 f1 = *(const float4*)(aggH + (size_t)n * H + q * 8 + 4);
        const float4 f2 = *(const float4*)(aggH + (size_t)n * H + 32 + q * 8);
        const float4 f3 = *(const float4*)(aggH + (size_t)n * H + 32 + q * 8 + 4);
        a2[0] = bf16r(f0.x); a2[1] = bf16r(f0.y); a2[2] = bf16r(f0.z); a2[3] = bf16r(f0.w);
        a2[4] = bf16r(f1.x); a2[5] = bf16r(f1.y); a2[6] = bf16r(f1.z); a2[7] = bf16r(f1.w);
        a3[0] = bf16r(f2.x); a3[1] = bf16r(f2.y); a3[2] = bf16r(f2.z); a3[3] = bf16r(f2.w);
        a3[4] = bf16r(f3.x); a3[5] = bf16r(f3.y); a3[6] = bf16r(f3.z); a3[7] = bf16r(f3.w);
    }

    float b1v[4], b2v[4], c2uv[4];
#pragma unroll
    for (int nt = 0; nt < 4; ++nt) {
        b1v[nt] = b1[nt * 16 + m15];
        b2v[nt] = b2[nt * 16 + m15];
        c2uv[nt] = c2u[nt * 16 + m15];
    }
    float degf[4];
#pragma unroll
    for (int r = 0; r < 4; ++r) {
        const int nn = n0 + w * 16 + q * 4 + r;
        degf[r] = (nn < N) ? (float)degc[nn] : 0.f;
    }

    floatx4 acc[4] = {{0,0,0,0},{0,0,0,0},{0,0,0,0},{0,0,0,0}};
#pragma unroll
    for (int nt = 0; nt < 4; ++nt) {
        acc[nt] = __builtin_amdgcn_mfma_f32_16x16x32_bf16(a0, *(const short8*)(W1f + ((0*4+nt)*64 + l)*8), acc[nt], 0,0,0);
        acc[nt] = __builtin_amdgcn_mfma_f32_16x16x32_bf16(a1, *(const short8*)(W1f + ((1*4+nt)*64 + l)*8), acc[nt], 0,0,0);
        acc[nt] = __builtin_amdgcn_mfma_f32_16x16x32_bf16(a2, *(const short8*)(W1f + ((2*4+nt)*64 + l)*8), acc[nt], 0,0,0);
        acc[nt] = __builtin_amdgcn_mfma_f32_16x16x32_bf16(a3, *(const short8*)(W1f + ((3*4+nt)*64 + l)*8), acc[nt], 0,0,0);
    }

#pragma unroll
    for (int nt = 0; nt < 4; ++nt)
#pragma unroll
        for (int r = 0; r < 4; ++r)
            C1[(q * 4 + r) * 72 + nt * 16 + m15] =
                bf16r(fmaxf(acc[nt][r] + b1v[nt] + degf[r] * c2uv[nt], 0.f));

    const short8 p0 = *(const short8*)(C1 + m15 * 72 + q * 8);
    const short8 p1 = *(const short8*)(C1 + m15 * 72 + 32 + q * 8);

    floatx4 c2[4] = {{0,0,0,0},{0,0,0,0},{0,0,0,0},{0,0,0,0}};
#pragma unroll
    for (int nt = 0; nt < 4; ++nt) {
        c2[nt] = __builtin_amdgcn_mfma_f32_16x16x32_bf16(p0, *(const short8*)(W2f + ((0*4+nt)*64 + l)*8), c2[nt], 0,0,0);
        c2[nt] = __builtin_amdgcn_mfma_f32_16x16x32_bf16(p1, *(const short8*)(W2f + ((1*4+nt)*64 + l)*8), c2[nt], 0,0,0);
    }

    // outer relu -> C2 -> register run-merge mean-pool
#pragma unroll
    for (int nt = 0; nt < 4; ++nt)
#pragma unroll
        for (int r = 0; r < 4; ++r)
            C2[(q * 4 + r) * 66 + nt * 16 + m15] = fmaxf(c2[nt][r] + b2v[nt], 0.f);

    const int bi = ok ? batch[n] : -1;
    int bm[16];
#pragma unroll
    for (int mm = 0; mm < 16; ++mm)
        bm[mm] = __builtin_amdgcn_readlane(bi, mm);
    float v[16];
#pragma unroll
    for (int mm = 0; mm < 16; ++mm) v[mm] = C2[mm * 66 + l];

    float run = v[0];
    int cur = bm[0];
    int len = 1;
#pragma unroll
    for (int mm = 1; mm < 16; ++mm) {
        if (bm[mm] != cur) {
            if (cur >= 0) {
                atomicAdd(&pooled[(size_t)cur * H + l], run);
                if (l == 0) atomicAdd(&counts[cur], (float)len);
            }
            run = v[mm]; cur = bm[mm]; len = 1;
        } else {
            run += v[mm]; ++len;
        }
    }
    if (cur >= 0) {
        atomicAdd(&pooled[(size_t)cur * H + l], run);
        if (l == 0) atomicAdd(&counts[cur], (float)len);
    }
}

// ---------------- head ----------------
__global__ void head_kernel(const float* __restrict__ pooled,
                            const float* __restrict__ counts,
                            const float* __restrict__ lin1w,
                            const float* __restrict__ lin1b,
                            const float* __restrict__ lin2w,
                            const float* __restrict__ lin2b,
                            float* __restrict__ out, int G)
{
    int g = blockIdx.x;
    int j = threadIdx.x;
    __shared__ float p[H];
    float c = fmaxf(counts[g], 1.0f);
    p[j] = pooled[(size_t)g * H + j] / c;
    __syncthreads();

    float accj = lin1b[j];
#pragma unroll
    for (int k = 0; k < H; ++k) accj = fmaf(p[k], lin1w[k * H + j], accj);
    accj = fmaxf(accj, 0.0f) * lin2w[j];
#pragma unroll
    for (int off = 32; off >= 1; off >>= 1) accj += __shfl_down(accj, off);
    if (j == 0) out[g] = accj + lin2b[0];
}

extern "C" void kernel_launch(void* const* d_in, const int* in_sizes, int n_in,
                              void* d_out, int out_size, void* d_ws, size_t ws_size,
                              hipStream_t stream)
{
    const float* x      = (const float*)d_in[0];
    const int*   eidx   = (const int*)d_in[1];
    const float* ea     = (const float*)d_in[2];
    const int*   batch  = (const int*)d_in[3];
    const float* mW1    = (const float*)d_in[4];
    const float* mb1    = (const float*)d_in[5];
    const float* mW2    = (const float*)d_in[6];
    const float* mb2    = (const float*)d_in[7];
    const float* uW1    = (const float*)d_in[8];
    const float* ub1    = (const float*)d_in[9];
    const float* uW2    = (const float*)d_in[10];
    const float* ub2    = (const float*)d_in[11];
    const float* lin1w  = (const float*)d_in[12];
    const float* lin1b  = (const float*)d_in[13];
    const float* lin2w  = (const float*)d_in[14];
    const float* lin2b  = (const float*)d_in[15];

    const int N = in_sizes[0] / H;
    const int E = in_sizes[1] / 2;
    const int G = out_size;

    // ---- workspace ----
    short* mW1f = (short*)d_ws;                  // 30720 shorts
    short* nW1f = mW1f + 30720;                  // 24576
    short* uW2f = nW1f + 24576;                  // 12288
    short* x16  = uW2f + 12288;                  // N*H
    short* h16A = x16  + (size_t)N * H;
    short* h16B = h16A + (size_t)N * H;
    short* P16  = h16B + (size_t)N * H;          // N*H bf16
    short* Q16  = P16  + (size_t)N * H;          // N*H bf16
    float* nW1cat = (float*)(Q16 + (size_t)N * H);     // 3*128*64
    float* c2u    = nW1cat + 3 * 128 * 64;             // 192
    char*  pch  = (char*)(c2u + 192);
    pch = (char*)(((uintptr_t)pch + 63) & ~(uintptr_t)63);
    char* rec   = pch;                pch += (size_t)E * 64;   // 64B records
    int* offs   = (int*)pch;          pch += (size_t)N * 4;
    int* bsum   = (int*)pch;          pch += 256;
    int* rank4  = (int*)pch;          pch += (size_t)E * 4;
    // contiguous zero region: [cnt N ints][agg3 3*N*H][pooled G*H][counts G]
    int*   cnt    = (int*)pch;
    float* agg3   = (float*)(pch + (size_t)N * 4);
    float* pooled = agg3 + (size_t)3 * N * H;
    float* counts = pooled + (size_t)G * H;
    const size_t zero_bytes = (size_t)N * 4 + ((size_t)3 * N * H + (size_t)G * H + G) * 4;

    const int* esrc = eidx;
    const int* edst = eidx + E;

    // ---- prep: fused node weights, then frag packing + x16 ----
    prep_w2u<<<(24768 + 255) / 256, 256, 0, stream>>>(mW2, uW1, mb2, nW1cat, c2u);
    {
        const int n8 = N * H / 8;
        const int total = T_MW1 + T_NW1 + T_UW2 + n8;
        prep_all<<<(total + 255) / 256, 256, 0, stream>>>(
            mW1, nW1cat, uW2, x, mW1f, nW1f, uW2f, x16, n8);
    }

    hipMemsetAsync(cnt, 0, zero_bytes, stream);

    // ---- dst-sort prep: single atomic pass + deterministic full-line scatter ----
    rank_pass<<<(E + 255) / 256, 256, 0, stream>>>(edst, cnt, rank4, E);
    {
        const int nb = (N + 1023) / 1024;
        scan_block<<<nb, 1024, 0, stream>>>(cnt, offs, bsum, N);
        scan_bsum<<<1, 64, 0, stream>>>(bsum, nb);
        add_bsum<<<(N + 255) / 256, 256, 0, stream>>>(offs, bsum, N);
    }
    reorder_scatter<<<(E + 255) / 256, 256, 0, stream>>>(
        esrc, edst, rank4, offs, ea, rec, E);

    const short* hin = x16;
    short* houts16[3] = {h16A, h16B, nullptr};
    const int nEB = E / 64;                      // 12500 exact
    const int nNB = (N + 63) / 64;

    // layer-0 P/Q from x16; layers 1,2 produced fused inside node_update_fused
    pq_gemm<<<nNB, 256, 0, stream>>>(x16, mW1f, P16, Q16, N);

    for (int lyr = 0; lyr < 3; ++lyr) {
        float* agg = agg3 + (size_t)lyr * N * H;
        edge_msg_mfma<<<nEB, 256, 0, stream>>>(
            P16, Q16, rec,
            mW1f + (size_t)lyr * 10240 + 8192,   // kt=4 block = ea weights
            mb1 + (size_t)lyr * H,
            agg);
        if (lyr < 2) {
            node_update_fused<<<nNB, 256, 0, stream>>>(
                hin, agg,
                nW1f + (size_t)lyr * 8192, ub1 + (size_t)lyr * H,
                uW2f + (size_t)lyr * 4096, ub2 + (size_t)lyr * H,
                c2u + (size_t)lyr * 64, cnt,
                houts16[lyr],
                mW1f + (size_t)(lyr + 1) * 10240,
                P16, Q16, N);
            hin = houts16[lyr];
        } else {
            node_update_final<<<nNB, 256, 0, stream>>>(
                hin, agg,
                nW1f + (size_t)lyr * 8192, ub1 + (size_t)lyr * H,
                uW2f + (size_t)lyr * 4096, ub2 + (size_t)lyr * H,
                c2u + (size_t)lyr * 64, cnt,
                batch, pooled, counts, N);
        }
    }

    head_kernel<<<G, H, 0, stream>>>(pooled, counts, lin1w, lin1b, lin2w, lin2b,
                                     (float*)d_out, G);
}

// Round 14
// 355.237 us; speedup vs baseline: 1.0187x; 1.0095x over previous
//
#include <hip/hip_runtime.h>

#define H 64

typedef __attribute__((ext_vector_type(8))) short short8;
typedef __attribute__((ext_vector_type(4))) float floatx4;

__device__ __forceinline__ short bf16r(float f) {
    union { float f; unsigned u; } v; v.f = f;
    unsigned r = v.u + 0x7FFFu + ((v.u >> 16) & 1u);
    return (short)(r >> 16);
}

__device__ __forceinline__ float b2f(unsigned short s) {
    union { unsigned u; float f; } v; v.u = ((unsigned)s) << 16; return v.f;
}

// ---------------- mega-prep: weight packing + W2u inline + x16 + rank ---------
__device__ __forceinline__ void pack_one(const float* W, short* out, int K, int KT, int tid)
{
    const int lane = tid & 63;
    const int nt = (tid >> 6) & 3;
    const int lk = tid >> 8;          // lay*KT + kt
    const int kt = lk % KT;
    const int lay = lk / KT;
    const int n = nt * 16 + (lane & 15);
    const int kbase = kt * 32 + ((lane >> 4) & 3) * 8;
    short8 v;
#pragma unroll
    for (int j = 0; j < 8; ++j) {
        const int k = kbase + j;
        const float w = (k < K) ? W[((size_t)lay * K + k) * H + n] : 0.f;
        v[j] = bf16r(w);
    }
    *(short8*)(out + (size_t)tid * 8) = v;
}

// node fused W1 = [uW1a ; mW2@uW1b] packed directly (W2u dot inline, same fp32
// loop order as the old prep_w2u -> bit-identical values)
__device__ __forceinline__ void pack_nw1(const float* uW1, const float* mW2,
                                         short* out, int tid)
{
    const int lane = tid & 63;
    const int nt = (tid >> 6) & 3;
    const int lk = tid >> 8;          // lay*4 + kt
    const int kt = lk & 3;
    const int lay = lk >> 2;
    const int n = nt * 16 + (lane & 15);
    const int kbase = kt * 32 + ((lane >> 4) & 3) * 8;
    short8 v;
#pragma unroll
    for (int j = 0; j < 8; ++j) {
        const int k = kbase + j;
        float wv;
        if (k < 64) {
            wv = uW1[((size_t)lay * 128 + k) * H + n];
        } else {
            const int a = k - 64;
            float s = 0.f;
#pragma unroll 8
            for (int c = 0; c < 64; ++c)
                s += mW2[((size_t)lay * 64 + a) * 64 + c]
                   * uW1[((size_t)lay * 128 + 64 + c) * 64 + n];
            wv = s;
        }
        v[j] = bf16r(wv);
    }
    *(short8*)(out + (size_t)tid * 8) = v;
}

#define T_MW1 3840   // 3*5*4*64  (edge W1: K=144 padded to 160)
#define T_NW1 3072   // 3*4*4*64  (node fused W1: K=128, W2u inline)
#define T_UW2 1536   // 3*2*4*64
#define T_C2U 192    // c2u[l][j] = sum_c mb2[c]*uW1[64+c][j]

__global__ void prep_all(const float* __restrict__ mW1, const float* __restrict__ mW2,
                         const float* __restrict__ uW1, const float* __restrict__ mb2,
                         const float* __restrict__ uW2, const float* __restrict__ x,
                         const int* __restrict__ edst,
                         short* __restrict__ mW1f, short* __restrict__ nW1f,
                         short* __restrict__ uW2f, float* __restrict__ c2u,
                         short* __restrict__ x16,
                         int* __restrict__ cnt, int* __restrict__ rank4,
                         int n8, int E)
{
    int g = blockIdx.x * blockDim.x + threadIdx.x;
    if (g < T_MW1) { pack_one(mW1, mW1f, 144, 5, g); return; }
    g -= T_MW1;
    if (g < T_NW1) { pack_nw1(uW1, mW2, nW1f, g); return; }
    g -= T_NW1;
    if (g < T_UW2) { pack_one(uW2, uW2f, 64, 2, g); return; }
    g -= T_UW2;
    if (g < T_C2U) {
        const int l = g >> 6, j = g & 63;
        float s = 0.f;
#pragma unroll 8
        for (int c = 0; c < 64; ++c)
            s += mb2[l * 64 + c] * uW1[((size_t)l * 128 + 64 + c) * 64 + j];
        c2u[l * 64 + j] = s;
        return;
    }
    g -= T_C2U;
    if (g < n8) {
        const float4 a = ((const float4*)x)[2 * g];
        const float4 b = ((const float4*)x)[2 * g + 1];
        short8 v;
        v[0] = bf16r(a.x); v[1] = bf16r(a.y); v[2] = bf16r(a.z); v[3] = bf16r(a.w);
        v[4] = bf16r(b.x); v[5] = bf16r(b.y); v[6] = bf16r(b.z); v[7] = bf16r(b.w);
        ((short8*)x16)[g] = v;
        return;
    }
    g -= n8;
    if (g < E) rank4[g] = atomicAdd(&cnt[edst[g]], 1);   // cnt -> degrees
}

// ---------------- scan (block partials; add_bsum self-computes its prefix) ----
__global__ void scan_block(const int* __restrict__ cnt, int* __restrict__ offs,
                           int* __restrict__ bsum, int n)
{
    __shared__ int buf[1024];
    const int t = threadIdx.x;
    const int gid = blockIdx.x * 1024 + t;
    const int v = (gid < n) ? cnt[gid] : 0;
    buf[t] = v;
    __syncthreads();
#pragma unroll
    for (int off = 1; off < 1024; off <<= 1) {
        int x = (t >= off) ? buf[t - off] : 0;
        __syncthreads();
        buf[t] += x;
        __syncthreads();
    }
    if (gid < n) offs[gid] = buf[t] - v;          // exclusive within block
    if (t == 1023) bsum[blockIdx.x] = buf[1023];
}

__global__ void add_bsum(int* __restrict__ offs, const int* __restrict__ bsum, int n)
{
    __shared__ int base;
    const int t = threadIdx.x;
    const int gid = blockIdx.x * 256 + t;
    if (t == 0) {
        const int s = (blockIdx.x * 256) >> 10;   // block lies in ONE segment
        int acc = 0;
        for (int i = 0; i < s; ++i) acc += bsum[i];
        base = acc;
    }
    __syncthreads();
    if (gid < n) offs[gid] += base;
}

// deterministic scatter: p = offs[d] + rank[e]; all reads sequential, zero
// atomics, ONE random region: 64B-aligned record {src,dst,pad8,ea32,pad16}
__global__ void reorder_scatter(const int* __restrict__ esrc, const int* __restrict__ edst,
                                const int* __restrict__ rank4, const int* __restrict__ offs,
                                const float* __restrict__ ea,
                                char* __restrict__ rec, int E)
{
    int e = blockIdx.x * blockDim.x + threadIdx.x;
    if (e >= E) return;
    const int d = edst[e];
    const int p = offs[d] + rank4[e];
    const float4* r = (const float4*)(ea + (size_t)e * 16);
    const float4 a = r[0], b = r[1], c = r[2], d4 = r[3];
    short8 v0, v1;
    v0[0] = bf16r(a.x); v0[1] = bf16r(a.y); v0[2] = bf16r(a.z); v0[3] = bf16r(a.w);
    v0[4] = bf16r(b.x); v0[5] = bf16r(b.y); v0[6] = bf16r(b.z); v0[7] = bf16r(b.w);
    v1[0] = bf16r(c.x); v1[1] = bf16r(c.y); v1[2] = bf16r(c.z); v1[3] = bf16r(c.w);
    v1[4] = bf16r(d4.x); v1[5] = bf16r(d4.y); v1[6] = bf16r(d4.z); v1[7] = bf16r(d4.w);
    int4* rb = (int4*)(rec + (size_t)p * 64);
    rb[0] = make_int4(esrc[e], d, 0, 0);
    *(short8*)(rb + 1) = v0;
    *(short8*)(rb + 2) = v1;
    rb[3] = make_int4(0, 0, 0, 0);
}

// ---------------- layer-0 node GEMM: P = x@mW1a, Q = x@mW1b (bf16 out) --------
__global__ __launch_bounds__(256, 5)
void pq_gemm(const short* __restrict__ h16, const short* __restrict__ W1fl,
             short* __restrict__ P16, short* __restrict__ Q16, int N)
{
    const int t = threadIdx.x;
    const int w = t >> 6, l = t & 63, q = l >> 4, m15 = l & 15;
    const int n0 = blockIdx.x * 64;
    const int n = n0 + w * 16 + m15;
    const bool ok = n < N;

    short8 a0 = {0,0,0,0,0,0,0,0}, a1 = a0;
    if (ok) {
        a0 = *(const short8*)(h16 + (size_t)n * H + q * 8);
        a1 = *(const short8*)(h16 + (size_t)n * H + 32 + q * 8);
    }

    floatx4 pa[4] = {{0,0,0,0},{0,0,0,0},{0,0,0,0},{0,0,0,0}};
    floatx4 qa[4] = {{0,0,0,0},{0,0,0,0},{0,0,0,0},{0,0,0,0}};
#pragma unroll
    for (int nt = 0; nt < 4; ++nt) {
        pa[nt] = __builtin_amdgcn_mfma_f32_16x16x32_bf16(a0, *(const short8*)(W1fl + ((0*4+nt)*64 + l)*8), pa[nt], 0,0,0);
        pa[nt] = __builtin_amdgcn_mfma_f32_16x16x32_bf16(a1, *(const short8*)(W1fl + ((1*4+nt)*64 + l)*8), pa[nt], 0,0,0);
        qa[nt] = __builtin_amdgcn_mfma_f32_16x16x32_bf16(a0, *(const short8*)(W1fl + ((2*4+nt)*64 + l)*8), qa[nt], 0,0,0);
        qa[nt] = __builtin_amdgcn_mfma_f32_16x16x32_bf16(a1, *(const short8*)(W1fl + ((3*4+nt)*64 + l)*8), qa[nt], 0,0,0);
    }
#pragma unroll
    for (int nt = 0; nt < 4; ++nt)
#pragma unroll
        for (int r = 0; r < 4; ++r) {
            const int nn = n0 + w * 16 + q * 4 + r;
            if (nn < N) {
                P16[(size_t)nn * H + nt * 16 + m15] = bf16r(pa[nt][r]);
                Q16[(size_t)nn * H + nt * 16 + m15] = bf16r(qa[nt][r]);
            }
        }
}

// ---------------- edge kernel: z = P[dst]+Q[src]+ea@W1c+b1; scatter relu(z) ----
__global__ __launch_bounds__(256, 5)
void edge_msg_mfma(const short* __restrict__ P16, const short* __restrict__ Q16,
                   const char* __restrict__ rec,
                   const short* __restrict__ W1cf, const float* __restrict__ b1,
                   float* __restrict__ aggH)
{
    __shared__ float smf[4 * 1056];          // 4 waves x [16][66] fp32
    const int t = threadIdx.x;
    const int w = t >> 6, l = t & 63, q = l >> 4, m15 = l & 15;
    const int i = blockIdx.x * 64 + w * 16 + m15;
    const char* rbase = rec + (size_t)i * 64;
    const int2 sd = *(const int2*)rbase;
    const int s = sd.x, d = sd.y;
    float* C2 = smf + w * 1056;

    int dm[16], sm[16];
#pragma unroll
    for (int mm = 0; mm < 16; ++mm) {
        dm[mm] = __builtin_amdgcn_readlane(d, mm);
        sm[mm] = __builtin_amdgcn_readlane(s, mm);
    }
    float pv[16], qv[16];
#pragma unroll
    for (int mm = 0; mm < 16; ++mm) {
        pv[mm] = b2f((unsigned short)P16[(size_t)dm[mm] * H + l]);
        qv[mm] = b2f((unsigned short)Q16[(size_t)sm[mm] * H + l]);
    }
    const float b1l = b1[l];

    short8 a4 = {0, 0, 0, 0, 0, 0, 0, 0};
    if (q < 2) a4 = *(const short8*)(rbase + 16 + q * 16);

    floatx4 r4[4];
#pragma unroll
    for (int nt = 0; nt < 4; ++nt) {
        floatx4 z0 = {0, 0, 0, 0};
        r4[nt] = __builtin_amdgcn_mfma_f32_16x16x32_bf16(a4, *(const short8*)(W1cf + (nt*64 + l)*8), z0, 0,0,0);
    }
#pragma unroll
    for (int nt = 0; nt < 4; ++nt)
#pragma unroll
        for (int r = 0; r < 4; ++r)
            C2[(q * 4 + r) * 66 + nt * 16 + m15] = r4[nt][r];

    float run; int cur;
    {
        run = fmaxf(C2[l] + pv[0] + qv[0] + b1l, 0.f);
        cur = dm[0];
    }
#pragma unroll
    for (int mm = 1; mm < 16; ++mm) {
        const float val = fmaxf(C2[mm * 66 + l] + pv[mm] + qv[mm] + b1l, 0.f);
        if (dm[mm] != cur) {
            atomicAdd(&aggH[(size_t)cur * H + l], run);
            run = val; cur = dm[mm];
        } else {
            run += val;
        }
    }
    atomicAdd(&aggH[(size_t)cur * H + l], run);
}

// ---------------- node-update MLP (layers 0,1): + fused next-layer P/Q --------
__global__ __launch_bounds__(256, 4)
void node_update_fused(const short* __restrict__ h16,
                       const float* __restrict__ aggH,
                       const short* __restrict__ W1f, const float* __restrict__ b1,
                       const short* __restrict__ W2f, const float* __restrict__ b2,
                       const float* __restrict__ c2u, const int* __restrict__ degc,
                       short* __restrict__ h16out,
                       const short* __restrict__ W1fn,   // next-layer mW1 frags
                       short* __restrict__ P16o, short* __restrict__ Q16o,
                       int N)
{
    __shared__ char smraw[16896];
    const int t = threadIdx.x;
    const int w = t >> 6, l = t & 63, q = l >> 4, m15 = l & 15;
    const int n0 = blockIdx.x * 64;
    const int n = n0 + w * 16 + m15;
    const bool ok = n < N;

    short* C1 = (short*)(smraw + w * 4224);

    short8 a0 = {0,0,0,0,0,0,0,0}, a1 = a0, a2 = a0, a3 = a0;
    if (ok) {
        a0 = *(const short8*)(h16 + (size_t)n * H + q * 8);
        a1 = *(const short8*)(h16 + (size_t)n * H + 32 + q * 8);
        const float4 f0 = *(const float4*)(aggH + (size_t)n * H + q * 8);
        const float4 f1 = *(const float4*)(aggH + (size_t)n * H + q * 8 + 4);
        const float4 f2 = *(const float4*)(aggH + (size_t)n * H + 32 + q * 8);
        const float4 f3 = *(const float4*)(aggH + (size_t)n * H + 32 + q * 8 + 4);
        a2[0] = bf16r(f0.x); a2[1] = bf16r(f0.y); a2[2] = bf16r(f0.z); a2[3] = bf16r(f0.w);
        a2[4] = bf16r(f1.x); a2[5] = bf16r(f1.y); a2[6] = bf16r(f1.z); a2[7] = bf16r(f1.w);
        a3[0] = bf16r(f2.x); a3[1] = bf16r(f2.y); a3[2] = bf16r(f2.z); a3[3] = bf16r(f2.w);
        a3[4] = bf16r(f3.x); a3[5] = bf16r(f3.y); a3[6] = bf16r(f3.z); a3[7] = bf16r(f3.w);
    }

    float b1v[4], b2v[4], c2uv[4];
#pragma unroll
    for (int nt = 0; nt < 4; ++nt) {
        b1v[nt] = b1[nt * 16 + m15];
        b2v[nt] = b2[nt * 16 + m15];
        c2uv[nt] = c2u[nt * 16 + m15];
    }
    float degf[4];
#pragma unroll
    for (int r = 0; r < 4; ++r) {
        const int nn = n0 + w * 16 + q * 4 + r;
        degf[r] = (nn < N) ? (float)degc[nn] : 0.f;
    }

    floatx4 acc[4] = {{0,0,0,0},{0,0,0,0},{0,0,0,0},{0,0,0,0}};
#pragma unroll
    for (int nt = 0; nt < 4; ++nt) {
        acc[nt] = __builtin_amdgcn_mfma_f32_16x16x32_bf16(a0, *(const short8*)(W1f + ((0*4+nt)*64 + l)*8), acc[nt], 0,0,0);
        acc[nt] = __builtin_amdgcn_mfma_f32_16x16x32_bf16(a1, *(const short8*)(W1f + ((1*4+nt)*64 + l)*8), acc[nt], 0,0,0);
        acc[nt] = __builtin_amdgcn_mfma_f32_16x16x32_bf16(a2, *(const short8*)(W1f + ((2*4+nt)*64 + l)*8), acc[nt], 0,0,0);
        acc[nt] = __builtin_amdgcn_mfma_f32_16x16x32_bf16(a3, *(const short8*)(W1f + ((3*4+nt)*64 + l)*8), acc[nt], 0,0,0);
    }

#pragma unroll
    for (int nt = 0; nt < 4; ++nt)
#pragma unroll
        for (int r = 0; r < 4; ++r)
            C1[(q * 4 + r) * 72 + nt * 16 + m15] =
                bf16r(fmaxf(acc[nt][r] + b1v[nt] + degf[r] * c2uv[nt], 0.f));

    const short8 p0 = *(const short8*)(C1 + m15 * 72 + q * 8);
    const short8 p1 = *(const short8*)(C1 + m15 * 72 + 32 + q * 8);

    floatx4 c2[4] = {{0,0,0,0},{0,0,0,0},{0,0,0,0},{0,0,0,0}};
#pragma unroll
    for (int nt = 0; nt < 4; ++nt) {
        c2[nt] = __builtin_amdgcn_mfma_f32_16x16x32_bf16(p0, *(const short8*)(W2f + ((0*4+nt)*64 + l)*8), c2[nt], 0,0,0);
        c2[nt] = __builtin_amdgcn_mfma_f32_16x16x32_bf16(p1, *(const short8*)(W2f + ((1*4+nt)*64 + l)*8), c2[nt], 0,0,0);
    }

    // h_out bf16: to global AND to wave-private C1 (A-frag staging for P/Q)
#pragma unroll
    for (int nt = 0; nt < 4; ++nt)
#pragma unroll
        for (int r = 0; r < 4; ++r) {
            const short hv = bf16r(fmaxf(c2[nt][r] + b2v[nt], 0.f));
            C1[(q * 4 + r) * 72 + nt * 16 + m15] = hv;
            const int nn = n0 + w * 16 + q * 4 + r;
            if (nn < N)
                h16out[(size_t)nn * H + nt * 16 + m15] = hv;
        }

    const short8 h0 = *(const short8*)(C1 + m15 * 72 + q * 8);
    const short8 h1 = *(const short8*)(C1 + m15 * 72 + 32 + q * 8);
    floatx4 pa[4] = {{0,0,0,0},{0,0,0,0},{0,0,0,0},{0,0,0,0}};
    floatx4 qa[4] = {{0,0,0,0},{0,0,0,0},{0,0,0,0},{0,0,0,0}};
#pragma unroll
    for (int nt = 0; nt < 4; ++nt) {
        pa[nt] = __builtin_amdgcn_mfma_f32_16x16x32_bf16(h0, *(const short8*)(W1fn + ((0*4+nt)*64 + l)*8), pa[nt], 0,0,0);
        pa[nt] = __builtin_amdgcn_mfma_f32_16x16x32_bf16(h1, *(const short8*)(W1fn + ((1*4+nt)*64 + l)*8), pa[nt], 0,0,0);
        qa[nt] = __builtin_amdgcn_mfma_f32_16x16x32_bf16(h0, *(const short8*)(W1fn + ((2*4+nt)*64 + l)*8), qa[nt], 0,0,0);
        qa[nt] = __builtin_amdgcn_mfma_f32_16x16x32_bf16(h1, *(const short8*)(W1fn + ((3*4+nt)*64 + l)*8), qa[nt], 0,0,0);
    }
#pragma unroll
    for (int nt = 0; nt < 4; ++nt)
#pragma unroll
        for (int r = 0; r < 4; ++r) {
            const int nn = n0 + w * 16 + q * 4 + r;
            if (nn < N) {
                P16o[(size_t)nn * H + nt * 16 + m15] = bf16r(pa[nt][r]);
                Q16o[(size_t)nn * H + nt * 16 + m15] = bf16r(qa[nt][r]);
            }
        }
}

// ---------------- node-update MLP (final layer): fused mean-pool --------------
__global__ __launch_bounds__(256, 5)
void node_update_final(const short* __restrict__ h16,
                       const float* __restrict__ aggH,
                       const short* __restrict__ W1f, const float* __restrict__ b1,
                       const short* __restrict__ W2f, const float* __restrict__ b2,
                       const float* __restrict__ c2u, const int* __restrict__ degc,
                       const int* __restrict__ batch,
                       float* __restrict__ pooled, float* __restrict__ counts,
                       int N)
{
    __shared__ char smraw[16896];
    const int t = threadIdx.x;
    const int w = t >> 6, l = t & 63, q = l >> 4, m15 = l & 15;
    const int n0 = blockIdx.x * 64;
    const int n = n0 + w * 16 + m15;
    const bool ok = n < N;

    short* C1 = (short*)(smraw + w * 4224);
    float* C2 = (float*)(smraw + w * 4224);

    short8 a0 = {0,0,0,0,0,0,0,0}, a1 = a0, a2 = a0, a3 = a0;
    if (ok) {
        a0 = *(const short8*)(h16 + (size_t)n * H + q * 8);
        a1 = *(const short8*)(h16 + (size_t)n * H + 32 + q * 8);
        const float4 f0 = *(const float4*)(aggH + (size_t)n * H + q * 8);
        const float4 f1 = *(const float4*)(aggH + (size_t)n * H + q * 8 + 4);
        const float4 f2 = *(const float4*)(aggH + (size_t)n * H + 32 + q * 8);
        const float4 f3 = *(const float4*)(aggH + (size_t)n * H + 32 + q * 8 + 4);
        a2[0] = bf16r(f0.x); a2[1] = bf16r(f0.y); a2[2] = bf16r(f0.z); a2[3] = bf16r(f0.w);
        a2[4] = bf16r(f1.x); a2[5] = bf16r(f1.y); a2[6] = bf16r(f1.z); a2[7] = bf16r(f1.w);
        a3[0] = bf16r(f2.x); a3[1] = bf16r(f2.y); a3[2] = bf16r(f2.z); a3[3] = bf16r(f2.w);
        a3[4] = bf16r(f3.x); a3[5] = bf16r(f3.y); a3[6] = bf16r(f3.z); a3[7] = bf16r(f3.w);
    }

    float b1v[4], b2v[4], c2uv[4];
#pragma unroll
    for (int nt = 0; nt < 4; ++nt) {
        b1v[nt] = b1[nt * 16 + m15];
        b2v[nt] = b2[nt * 16 + m15];
        c2uv[nt] = c2u[nt * 16 + m15];
    }
    float degf[4];
#pragma unroll
    for (int r = 0; r < 4; ++r) {
        const int nn = n0 + w * 16 + q * 4 + r;
        degf[r] = (nn < N) ? (float)degc[nn] : 0.f;
    }

    floatx4 acc[4] = {{0,0,0,0},{0,0,0,0},{0,0,0,0},{0,0,0,0}};
#pragma unroll
    for (int nt = 0; nt < 4; ++nt) {
        acc[nt] = __builtin_amdgcn_mfma_f32_16x16x32_bf16(a0, *(const short8*)(W1f + ((0*4+nt)*64 + l)*8), acc[nt], 0,0,0);
        acc[nt] = __builtin_amdgcn_mfma_f32_16x16x32_bf16(a1, *(const short8*)(W1f + ((1*4+nt)*64 + l)*8), acc[nt], 0,0,0);
        acc[nt] = __builtin_amdgcn_mfma_f32_16x16x32_bf16(a2, *(const short8*)(W1f + ((2*4+nt)*64 + l)*8), acc[nt], 0,0,0);
        acc[nt] = __builtin_amdgcn_mfma_f32_16x16x32_bf16(a3, *(const short8*)(W1f + ((3*4+nt)*64 + l)*8), acc[nt], 0,0,0);
    }

#pragma unroll
    for (int nt = 0; nt < 4; ++nt)
#pragma unroll
        for (int r = 0; r < 4; ++r)
            C1[(q * 4 + r) * 72 + nt * 16 + m15] =
                bf16r(fmaxf(acc[nt][r] + b1v[nt] + degf[r] * c2uv[nt], 0.f));

    const short8 p0 = *(const short8*)(C1 + m15 * 72 + q * 8);
    const short8 p1 = *(const short8*)(C1 + m15 * 72 + 32 + q * 8);

    floatx4 c2[4] = {{0,0,0,0},{0,0,0,0},{0,0,0,0},{0,0,0,0}};
#pragma unroll
    for (int nt = 0; nt < 4; ++nt) {
        c2[nt] = __builtin_amdgcn_mfma_f32_16x16x32_bf16(p0, *(const short8*)(W2f + ((0*4+nt)*64 + l)*8), c2[nt], 0,0,0);
        c2[nt] = __builtin_amdgcn_mfma_f32_16x16x32_bf16(p1, *(const short8*)(W2f + ((1*4+nt)*64 + l)*8), c2[nt], 0,0,0);
    }

    // outer relu -> C2 -> register run-merge mean-pool
#pragma unroll
    for (int nt = 0; nt < 4; ++nt)
#pragma unroll
        for (int r = 0; r < 4; ++r)
            C2[(q * 4 + r) * 66 + nt * 16 + m15] = fmaxf(c2[nt][r] + b2v[nt], 0.f);

    const int bi = ok ? batch[n] : -1;
    int bm[16];
#pragma unroll
    for (int mm = 0; mm < 16; ++mm)
        bm[mm] = __builtin_amdgcn_readlane(bi, mm);
    float v[16];
#pragma unroll
    for (int mm = 0; mm < 16; ++mm) v[mm] = C2[mm * 66 + l];

    float run = v[0];
    int cur = bm[0];
    int len = 1;
#pragma unroll
    for (int mm = 1; mm < 16; ++mm) {
        if (bm[mm] != cur) {
            if (cur >= 0) {
                atomicAdd(&pooled[(size_t)cur * H + l], run);
                if (l == 0) atomicAdd(&counts[cur], (float)len);
            }
            run = v[mm]; cur = bm[mm]; len = 1;
        } else {
            run += v[mm]; ++len;
        }
    }
    if (cur >= 0) {
        atomicAdd(&pooled[(size_t)cur * H + l], run);
        if (l == 0) atomicAdd(&counts[cur], (float)len);
    }
}

// ---------------- head ----------------
__global__ void head_kernel(const float* __restrict__ pooled,
                            const float* __restrict__ counts,
                            const float* __restrict__ lin1w,
                            const float* __restrict__ lin1b,
                            const float* __restrict__ lin2w,
                            const float* __restrict__ lin2b,
                            float* __restrict__ out, int G)
{
    int g = blockIdx.x;
    int j = threadIdx.x;
    __shared__ float p[H];
    float c = fmaxf(counts[g], 1.0f);
    p[j] = pooled[(size_t)g * H + j] / c;
    __syncthreads();

    float accj = lin1b[j];
#pragma unroll
    for (int k = 0; k < H; ++k) accj = fmaf(p[k], lin1w[k * H + j], accj);
    accj = fmaxf(accj, 0.0f) * lin2w[j];
#pragma unroll
    for (int off = 32; off >= 1; off >>= 1) accj += __shfl_down(accj, off);
    if (j == 0) out[g] = accj + lin2b[0];
}

extern "C" void kernel_launch(void* const* d_in, const int* in_sizes, int n_in,
                              void* d_out, int out_size, void* d_ws, size_t ws_size,
                              hipStream_t stream)
{
    const float* x      = (const float*)d_in[0];
    const int*   eidx   = (const int*)d_in[1];
    const float* ea     = (const float*)d_in[2];
    const int*   batch  = (const int*)d_in[3];
    const float* mW1    = (const float*)d_in[4];
    const float* mb1    = (const float*)d_in[5];
    const float* mW2    = (const float*)d_in[6];
    const float* mb2    = (const float*)d_in[7];
    const float* uW1    = (const float*)d_in[8];
    const float* ub1    = (const float*)d_in[9];
    const float* uW2    = (const float*)d_in[10];
    const float* ub2    = (const float*)d_in[11];
    const float* lin1w  = (const float*)d_in[12];
    const float* lin1b  = (const float*)d_in[13];
    const float* lin2w  = (const float*)d_in[14];
    const float* lin2b  = (const float*)d_in[15];

    const int N = in_sizes[0] / H;
    const int E = in_sizes[1] / 2;
    const int G = out_size;

    // ---- workspace ----
    short* mW1f = (short*)d_ws;                  // 30720 shorts
    short* nW1f = mW1f + 30720;                  // 24576
    short* uW2f = nW1f + 24576;                  // 12288
    short* x16  = uW2f + 12288;                  // N*H
    short* h16A = x16  + (size_t)N * H;
    short* h16B = h16A + (size_t)N * H;
    short* P16  = h16B + (size_t)N * H;          // N*H bf16
    short* Q16  = P16  + (size_t)N * H;          // N*H bf16
    float* c2u  = (float*)(Q16 + (size_t)N * H); // 192
    char*  pch  = (char*)(c2u + 192);
    pch = (char*)(((uintptr_t)pch + 63) & ~(uintptr_t)63);
    char* rec   = pch;                pch += (size_t)E * 64;   // 64B records
    int* offs   = (int*)pch;          pch += (size_t)N * 4;
    int* bsum   = (int*)pch;          pch += 256;
    int* rank4  = (int*)pch;          pch += (size_t)E * 4;
    // contiguous zero region: [cnt N ints][agg3 3*N*H][pooled G*H][counts G]
    int*   cnt    = (int*)pch;
    float* agg3   = (float*)(pch + (size_t)N * 4);
    float* pooled = agg3 + (size_t)3 * N * H;
    float* counts = pooled + (size_t)G * H;
    const size_t zero_bytes = (size_t)N * 4 + ((size_t)3 * N * H + (size_t)G * H + G) * 4;

    const int* esrc = eidx;
    const int* edst = eidx + E;

    // ---- memset FIRST (rank segment inside prep_all needs zeroed cnt) ----
    hipMemsetAsync(cnt, 0, zero_bytes, stream);

    // ---- mega-prep: weights (W2u inline) + c2u + x16 + rank, one kernel ----
    {
        const int n8 = N * H / 8;
        const int total = T_MW1 + T_NW1 + T_UW2 + T_C2U + n8 + E;
        prep_all<<<(total + 255) / 256, 256, 0, stream>>>(
            mW1, mW2, uW1, mb2, uW2, x, edst,
            mW1f, nW1f, uW2f, c2u, x16, cnt, rank4,
            n8, E);
    }

    // ---- scan (2 dispatches) + deterministic scatter ----
    {
        const int nb = (N + 1023) / 1024;
        scan_block<<<nb, 1024, 0, stream>>>(cnt, offs, bsum, N);
        add_bsum<<<(N + 255) / 256, 256, 0, stream>>>(offs, bsum, N);
    }
    reorder_scatter<<<(E + 255) / 256, 256, 0, stream>>>(
        esrc, edst, rank4, offs, ea, rec, E);

    const short* hin = x16;
    short* houts16[3] = {h16A, h16B, nullptr};
    const int nEB = E / 64;                      // 12500 exact
    const int nNB = (N + 63) / 64;

    // layer-0 P/Q from x16; layers 1,2 produced fused inside node_update_fused
    pq_gemm<<<nNB, 256, 0, stream>>>(x16, mW1f, P16, Q16, N);

    for (int lyr = 0; lyr < 3; ++lyr) {
        float* agg = agg3 + (size_t)lyr * N * H;
        edge_msg_mfma<<<nEB, 256, 0, stream>>>(
            P16, Q16, rec,
            mW1f + (size_t)lyr * 10240 + 8192,   // kt=4 block = ea weights
            mb1 + (size_t)lyr * H,
            agg);
        if (lyr < 2) {
            node_update_fused<<<nNB, 256, 0, stream>>>(
                hin, agg,
                nW1f + (size_t)lyr * 8192, ub1 + (size_t)lyr * H,
                uW2f + (size_t)lyr * 4096, ub2 + (size_t)lyr * H,
                c2u + (size_t)lyr * 64, cnt,
                houts16[lyr],
                mW1f + (size_t)(lyr + 1) * 10240,
                P16, Q16, N);
            hin = houts16[lyr];
        } else {
            node_update_final<<<nNB, 256, 0, stream>>>(
                hin, agg,
                nW1f + (size_t)lyr * 8192, ub1 + (size_t)lyr * H,
                uW2f + (size_t)lyr * 4096, ub2 + (size_t)lyr * H,
                c2u + (size_t)lyr * 64, cnt,
                batch, pooled, counts, N);
        }
    }

    head_kernel<<<G, H, 0, stream>>>(pooled, counts, lin1w, lin1b, lin2w, lin2b,
                                     (float*)d_out, G);
}